// Round 17
// baseline (243.394 us; speedup 1.0000x reference)
//
#include <hip/hip_runtime.h>
#include <hip/hip_bf16.h>

#define NN 8192
#define EE 40960
#define FIN 32
#define HH 64
#define GG 64

typedef __attribute__((ext_vector_type(4))) float f32x4;
typedef __attribute__((ext_vector_type(8))) short s16x8;
typedef __attribute__((ext_vector_type(4))) short s16x4;
typedef unsigned short ushort_t;

__device__ __forceinline__ unsigned short f2bf(float f) {
    union { float f; unsigned int u; } v; v.f = f;
    unsigned int u = v.u;
    return (unsigned short)((u + 0x7fffu + ((u >> 16) & 1u)) >> 16);
}

__device__ __forceinline__ float bf2f(unsigned short u) {
    union { unsigned int i; float f; } v; v.i = ((unsigned)u) << 16; return v.f;
}

__device__ __forceinline__ void gll16(const void* g, void* l) {
    // async global -> LDS, 16B per lane; LDS dest = wave-uniform base + lane*16
    __builtin_amdgcn_global_load_lds((__attribute__((address_space(1))) void*)g,
                                     (__attribute__((address_space(3))) void*)l, 16, 0, 0);
}

// ---------------- Bt build (coalesced LDS-transpose) + zeroing + layer-1 root -------
__global__ void btbuild_all_kernel(const float* __restrict__ w2a, const float* __restrict__ b2a, ushort_t* __restrict__ Bta,
                                   const float* __restrict__ w2b, const float* __restrict__ b2b, ushort_t* __restrict__ Btb,
                                   const float* __restrict__ w2c, const float* __restrict__ b2c, ushort_t* __restrict__ Btc,
                                   int* __restrict__ cnt, int* __restrict__ fill, float* __restrict__ stats,
                                   const float* __restrict__ x, const float* __restrict__ r1w,
                                   const float* __restrict__ r1b, float* __restrict__ rootbuf) {
    int bid = blockIdx.x;
    int t = threadIdx.x;

    if (bid < 195) {                          // Bt transpose, one (layer, step) per block
        __shared__ float ws[64 * 65];         // [i][o] padded: bank-conflict-free reads
        const float* w2; const float* b2; ushort_t* Bt; int IC, sh, s;
        if (bid < 65)       { w2 = w2a; b2 = b2a; Bt = Bta; IC = 32; sh = 5; s = bid; }
        else if (bid < 130) { w2 = w2b; b2 = b2b; Bt = Btb; IC = 64; sh = 6; s = bid - 65; }
        else                { w2 = w2c; b2 = b2c; Bt = Btc; IC = 64; sh = 6; s = bid - 130; }
        const int CH = IC >> 3;
        const int NEL = IC * 64;
        const float* src = (s < 64) ? (w2 + (size_t)s * NEL) : b2;
        for (int idx = t; idx < NEL; idx += 256) {     // coalesced: consecutive o
            int i = idx >> 6, o = idx & 63;
            ws[i * 65 + o] = src[idx];
        }
        __syncthreads();
        ushort_t* dst = Bt + (size_t)s * NEL;
        for (int fl = t; fl < NEL; fl += 256) {        // coalesced ushort stores
            int row = fl >> sh;
            int j = fl & (IC - 1);
            int q = j >> 3, w = j & 7;
            int c = q ^ (row & (CH - 1));
            int i = c * 8 + w;
            dst[fl] = f2bf(ws[i * 65 + row]);
        }
        return;
    }
    if (bid < 227) {                          // zero cnt/fill
        int b = bid - 195;
        cnt[b * 256 + t] = 0; fill[b * 256 + t] = 0;
        return;
    }
    if (bid == 227) { stats[t] = 0.f; return; }
    if (bid == 228) { if (t < 128) stats[256 + t] = 0.f; return; }

    // layer-1 root: 512 blocks, 16 nodes each
    {
        __shared__ float xs[16][36];
        __shared__ float rws[32 * 64];
        __shared__ float rbs[64];
        int blk = bid - 229;
        for (int j = t; j < 512; j += 256) { int r = j >> 5, i = j & 31; xs[r][i] = x[(size_t)(blk * 16 + r) * 32 + i]; }
        for (int i = t; i < 2048; i += 256) rws[i] = r1w[i];
        if (t < 64) rbs[t] = r1b[t];
        __syncthreads();
        int r = t >> 4, cg = (t & 15) * 4;
        f32x4 s = *(const f32x4*)&rbs[cg];
#pragma unroll 8
        for (int i = 0; i < 32; i++) {
            float xv = xs[r][i];
            s += xv * (*(const f32x4*)&rws[i * 64 + cg]);
        }
        *(f32x4*)&rootbuf[(size_t)(blk * 16 + r) * 64 + cg] = s;
    }
}

// ---------------- CSR build ----------------
__global__ void hist_kernel(const int* __restrict__ dst, int* __restrict__ cnt) {
    int e = blockIdx.x * 256 + threadIdx.x;
    if (e < EE) atomicAdd(&cnt[dst[e]], 1);
}

__global__ void scan_kernel(const int* __restrict__ cnt, int* __restrict__ row_ptr) {
    __shared__ int lds[1024];
    int t = threadIdx.x;
    int v[8]; int s = 0;
    int base = t * 8;
#pragma unroll
    for (int j = 0; j < 8; j++) { v[j] = s; s += cnt[base + j]; }
    lds[t] = s;
    __syncthreads();
    for (int off = 1; off < 1024; off <<= 1) {
        int add = (t >= off) ? lds[t - off] : 0;
        __syncthreads();
        lds[t] += add;
        __syncthreads();
    }
    int ex = lds[t] - s;
#pragma unroll
    for (int j = 0; j < 8; j++) row_ptr[base + j] = ex + v[j];
    if (t == 1023) row_ptr[NN] = lds[1023];
}

__global__ void scatter_kernel(const int* __restrict__ dst, const int* __restrict__ row_ptr,
                               int* __restrict__ fill, int* __restrict__ perm) {
    int e = blockIdx.x * 256 + threadIdx.x;
    if (e < EE) {
        int d = dst[e];
        int pos = row_ptr[d] + atomicAdd(&fill[d], 1);
        perm[pos] = e;
    }
}

// ---------------- NNConv message GEMM, pair-phase (2 k-steps per barrier) ----------
// h_t stored in BF16 (halves its LDS): IC=64 pair-phase fits 4 blocks/CU
// (bt 32KB + h_t 4KB + misc ~4.5KB = 40.4KB; 4x40.4 <= 160KB), so the per-phase
// L2 RTT is covered by 3 sibling blocks' compute. 33 barriers vs 65.
template<int IC>
__launch_bounds__(256, 4)
__global__ void conv_msg_pair_kernel(const float* __restrict__ eattr,
                                     const float* __restrict__ w1,
                                     const float* __restrict__ b1,
                                     const float* __restrict__ xin,
                                     const int* __restrict__ src,
                                     const int* __restrict__ perm,
                                     const ushort_t* __restrict__ Bt,
                                     float* __restrict__ msg) {
    constexpr int NKK  = IC / 32;
    constexpr int CH   = IC / 8;
    constexpr int TILE = IC * 64;        // ushorts per k-step tile
    constexpr int NQT  = TILE / 2048;    // 1 (IC32) / 2 (IC64)
    __shared__ ushort_t bt_lds[2][2 * TILE];
    __shared__ ushort_t h_t[2048];       // h transposed [k][e_local], BF16
    __shared__ float ea_s[32][9];
    __shared__ float w1s[512];
    __shared__ float b1s[64];
    __shared__ int eid_s[32];

    const int t = threadIdx.x;
    const int wave = t >> 6;
    const int l = t & 63;
    const int g = l >> 4;
    const int rlo = l & 15;
    const int e0 = blockIdx.x * 32;

    auto stage = [&](int buf, int phase) {
#pragma unroll
        for (int q = 0; q < 2 * NQT; ++q) {
            int off = q * 2048 + wave * 512;
            const ushort_t* gp = Bt + (size_t)(2 * phase) * TILE + off + l * 8;
            gll16(gp, &bt_lds[buf][off]);
        }
    };

    stage(0, 0);

    if (t < 32) eid_s[t] = perm[e0 + t];
    if (t < 64) b1s[t] = b1[t];
    for (int i = t; i < 512; i += 256) w1s[i] = w1[i];
    __syncthreads();

    { int e = t >> 3, i = t & 7; ea_s[e][i] = eattr[(size_t)eid_s[e] * 8 + i]; }

    s16x8 afrag[2][NKK];
#pragma unroll
    for (int m = 0; m < 2; ++m) {
        int row = m * 16 + rlo;
        int sn = src[eid_s[row]];
        const float* xp = xin + (size_t)sn * IC + g * 8;
#pragma unroll
        for (int kk = 0; kk < NKK; ++kk) {
            f32x4 a = *(const f32x4*)(xp + kk * 32);
            f32x4 b = *(const f32x4*)(xp + kk * 32 + 4);
            s16x8 fr;
            fr[0] = (short)f2bf(a[0]); fr[1] = (short)f2bf(a[1]);
            fr[2] = (short)f2bf(a[2]); fr[3] = (short)f2bf(a[3]);
            fr[4] = (short)f2bf(b[0]); fr[5] = (short)f2bf(b[1]);
            fr[6] = (short)f2bf(b[2]); fr[7] = (short)f2bf(b[3]);
            afrag[m][kk] = fr;
        }
    }
    __syncthreads();

#pragma unroll
    for (int j = 0; j < 8; ++j) {
        int idx = t + 256 * j;
        int k = idx >> 5, e = idx & 31;
        float s = b1s[k];
#pragma unroll
        for (int i = 0; i < 8; i++) s += ea_s[e][i] * w1s[i * 64 + k];
        h_t[idx] = f2bf(fmaxf(s, 0.f));
    }
    __syncthreads();

    f32x4 acc[2];
#pragma unroll
    for (int m = 0; m < 2; m++) acc[m] = (f32x4){0.f, 0.f, 0.f, 0.f};

    const int bcol = wave * 16 + rlo;
    const int bmask = bcol & (CH - 1);
    const f32x4 zf = (f32x4){0.f, 0.f, 0.f, 0.f};

    auto compute = [&](int buf, int sub, int step) {
        s16x8 bfr[NKK];
#pragma unroll
        for (int kk = 0; kk < NKK; kk++) {
            int q = (kk * 4 + g) ^ bmask;
            bfr[kk] = *(const s16x8*)&bt_lds[buf][sub * TILE + bcol * IC + q * 8];
        }
#pragma unroll
        for (int m = 0; m < 2; m++) {
            f32x4 P = __builtin_amdgcn_mfma_f32_16x16x32_bf16(afrag[m][0], bfr[0], zf, 0, 0, 0);
            if constexpr (NKK == 2)
                P = __builtin_amdgcn_mfma_f32_16x16x32_bf16(afrag[m][1], bfr[1], P, 0, 0, 0);
            if (step == 64) {
                acc[m] += P;
            } else {
                s16x4 hv = *(const s16x4*)&h_t[(step << 5) + m * 16 + (g << 2)];
                f32x4 h4;
                h4[0] = bf2f((unsigned short)hv[0]);
                h4[1] = bf2f((unsigned short)hv[1]);
                h4[2] = bf2f((unsigned short)hv[2]);
                h4[3] = bf2f((unsigned short)hv[3]);
                acc[m] += h4 * P;
            }
        }
    };

    for (int ph = 0; ph < 33; ++ph) {
        if (ph < 32) stage((ph + 1) & 1, ph + 1);
        const int buf = ph & 1;
        compute(buf, 0, 2 * ph);
        if (ph < 32) compute(buf, 1, 2 * ph + 1);
        __syncthreads();
    }

#pragma unroll
    for (int m = 0; m < 2; m++) {
        int row = e0 + m * 16 + (g << 2);
        float* mp = msg + (size_t)row * 64 + wave * 16 + rlo;
        mp[0] = acc[m][0]; mp[64] = acc[m][1]; mp[128] = acc[m][2]; mp[192] = acc[m][3];
    }
}

// ---------------- aggregate: y = seg_mean(msg) + rootbuf; fused BN stats ----------------
__global__ void aggregate_kernel(const float* __restrict__ msg, const int* __restrict__ row_ptr,
                                 const float* __restrict__ rootbuf,
                                 float* __restrict__ y, float* __restrict__ stats) {
    int t = threadIdx.x;
    int n = blockIdx.x * 16 + (t >> 4);
    int cg = (t & 15) * 4;
    int s = row_ptr[n], e = row_ptr[n + 1];
    f32x4 acc = (f32x4){0.f, 0.f, 0.f, 0.f};
    for (int j = s; j < e; ++j) {
        acc += *(const f32x4*)&msg[(size_t)j * 64 + cg];   // contiguous (dst-sorted)
    }
    float inv = 1.0f / fmaxf((float)(e - s), 1.0f);
    acc *= inv;
    acc += *(const f32x4*)&rootbuf[(size_t)n * 64 + cg];   // x@root_w + root_b (precomputed)
    *(f32x4*)&y[(size_t)n * 64 + cg] = acc;

    f32x4 a2 = acc * acc;
#pragma unroll
    for (int j = 0; j < 4; j++) {
        acc[j] += __shfl_xor(acc[j], 16); acc[j] += __shfl_xor(acc[j], 32);
        a2[j]  += __shfl_xor(a2[j], 16);  a2[j]  += __shfl_xor(a2[j], 32);
    }
    __shared__ float ls[4][64], lq[4][64];
    int w = t >> 6;
    if ((t & 63) < 16) {
#pragma unroll
        for (int j = 0; j < 4; j++) { ls[w][cg + j] = acc[j]; lq[w][cg + j] = a2[j]; }
    }
    __syncthreads();
    if (t < 64) {
        float S = ls[0][t] + ls[1][t] + ls[2][t] + ls[3][t];
        float Q = lq[0][t] + lq[1][t] + lq[2][t] + lq[3][t];
        atomicAdd(&stats[t], S);
        atomicAdd(&stats[64 + t], Q);
    }
}

// ---------------- BN apply + relu (+ residual) + NEXT layer's root GEMM ----------------
__global__ void bn_apply_root_kernel(const float* __restrict__ y, const float* __restrict__ stats,
                                     const float* __restrict__ gam, const float* __restrict__ bet,
                                     const float* __restrict__ res, float* __restrict__ xout,
                                     const float* __restrict__ rw, const float* __restrict__ rb,
                                     float* __restrict__ rootbuf) {
    __shared__ float xs[16][68];
    __shared__ float rws[64 * 64];   // 16 KB
    __shared__ float rbs[64];
    int t = threadIdx.x;
    for (int i = t; i < 4096; i += 256) rws[i] = rw[i];
    if (t < 64) rbs[t] = rb[t];
    int i4 = blockIdx.x * 256 + t;
    int row = t >> 4, cg = (t & 15) * 4;
    const float invN = 1.0f / (float)NN;
    f32x4 yv = *(const f32x4*)&y[(size_t)i4 * 4];
    f32x4 o;
#pragma unroll
    for (int j = 0; j < 4; j++) {
        int c = cg + j;
        float mean = stats[c] * invN;
        float var = stats[64 + c] * invN - mean * mean;
        float sc = rsqrtf(var + 1e-5f) * gam[c];
        o[j] = fmaxf((yv[j] - mean) * sc + bet[c], 0.f);
    }
    if (res) o += *(const f32x4*)&res[(size_t)i4 * 4];
    *(f32x4*)&xout[(size_t)i4 * 4] = o;
    *(f32x4*)&xs[row][cg] = o;
    __syncthreads();
    f32x4 s = *(const f32x4*)&rbs[cg];
#pragma unroll 8
    for (int i = 0; i < 64; i++) {
        float xv = xs[row][i];
        s += xv * (*(const f32x4*)&rws[i * 64 + cg]);
    }
    *(f32x4*)&rootbuf[(size_t)(blockIdx.x * 16 + row) * 64 + cg] = s;
}

// ---------------- BN3 + relu + residual + attention-gate (fused) ----------------
__global__ void bn_gate_kernel(const float* __restrict__ y, const float* __restrict__ stats,
                               const float* __restrict__ gam, const float* __restrict__ bet,
                               const float* __restrict__ res, float* __restrict__ xout,
                               const float* __restrict__ gw1, const float* __restrict__ gb1,
                               const float* __restrict__ gw2, const float* __restrict__ gb2,
                               float* __restrict__ gate) {
    __shared__ float x3s[64][68];   // stride 68: 16B-aligned f32x4 slots
    __shared__ float w1s[2048];
    __shared__ float b1s[32], w2s[32];
    __shared__ float b2s;
    int t = threadIdx.x;
    for (int i = t; i < 2048; i += 256) w1s[i] = gw1[i];
    if (t < 32) { b1s[t] = gb1[t]; w2s[t] = gw2[t]; }
    if (t == 0) b2s = gb2[0];
    const float invN = 1.0f / (float)NN;
    size_t base4 = (size_t)blockIdx.x * 1024;   // block covers 64 rows = 1024 f32x4
#pragma unroll
    for (int j = 0; j < 4; j++) {
        int i4l = j * 256 + t;
        int row = i4l >> 4, cg = (i4l & 15) * 4;
        f32x4 yv = *(const f32x4*)&y[(base4 + i4l) * 4];
        f32x4 o;
#pragma unroll
        for (int jj = 0; jj < 4; jj++) {
            int c = cg + jj;
            float mean = stats[c] * invN;
            float var = stats[64 + c] * invN - mean * mean;
            float sc = rsqrtf(var + 1e-5f) * gam[c];
            o[jj] = fmaxf((yv[jj] - mean) * sc + bet[c], 0.f);
        }
        o += *(const f32x4*)&res[(base4 + i4l) * 4];
        *(f32x4*)&xout[(base4 + i4l) * 4] = o;
        *(f32x4*)&x3s[row][cg] = o;
    }
    __syncthreads();
    // gate: 4 lanes per row, 8 hidden units each
    int w = t >> 6, l = t & 63;
    int row = w * 16 + (l >> 2), part = l & 3;
    float hacc[8];
#pragma unroll
    for (int j = 0; j < 8; j++) hacc[j] = b1s[part * 8 + j];
    for (int i = 0; i < 64; i++) {
        float xv = x3s[row][i];
#pragma unroll
        for (int j = 0; j < 8; j++) hacc[j] += xv * w1s[i * 32 + part * 8 + j];
    }
    float gv = 0.f;
#pragma unroll
    for (int j = 0; j < 8; j++) gv += fmaxf(hacc[j], 0.f) * w2s[part * 8 + j];
    gv += __shfl_xor(gv, 1); gv += __shfl_xor(gv, 2);
    if (part == 0) gate[blockIdx.x * 64 + row] = gv + b2s;
}

// ---------------- per-group softmax-weighted pool ----------------
__global__ void attn_pool_kernel(const float* __restrict__ x3, const float* __restrict__ gate,
                                 const int* __restrict__ batch, float* __restrict__ p) {
    int g = blockIdx.x;
    int t = threadIdx.x;
    int lo = 0, hi = NN;
    while (lo < hi) { int mid = (lo + hi) >> 1; if (batch[mid] < g) lo = mid + 1; else hi = mid; }
    int s = lo;
    hi = NN;
    while (lo < hi) { int mid = (lo + hi) >> 1; if (batch[mid] < g + 1) lo = mid + 1; else hi = mid; }
    int e = lo;

    __shared__ float red[4];
    __shared__ float sM, sZ;
    float m = -1e30f;
    for (int n = s + t; n < e; n += 256) m = fmaxf(m, gate[n]);
#pragma unroll
    for (int off = 1; off < 64; off <<= 1) m = fmaxf(m, __shfl_xor(m, off));
    if ((t & 63) == 0) red[t >> 6] = m;
    __syncthreads();
    if (t == 0) sM = fmaxf(fmaxf(red[0], red[1]), fmaxf(red[2], red[3]));
    __syncthreads();
    float z = 0.f;
    for (int n = s + t; n < e; n += 256) z += __expf(gate[n] - sM);
#pragma unroll
    for (int off = 1; off < 64; off <<= 1) z += __shfl_xor(z, off);
    if ((t & 63) == 0) red[t >> 6] = z;
    __syncthreads();
    if (t == 0) sZ = red[0] + red[1] + red[2] + red[3];
    __syncthreads();
    int w = t >> 6, c = t & 63;
    float acc = 0.f;
    for (int n = s + w; n < e; n += 4) acc += __expf(gate[n] - sM) * x3[(size_t)n * 64 + c];
    __shared__ float pa[4][64];
    pa[w][c] = acc;
    __syncthreads();
    if (t < 64) {
        float v = pa[0][t] + pa[1][t] + pa[2][t] + pa[3][t];
        p[g * 64 + t] = (sZ > 0.f) ? v / sZ : 0.f;
    }
}

// ---------------- head: fc1 + bn1 + relu (block owns 16 cols -> local stats) ----------------
__global__ void head1_kernel(const float* __restrict__ p, const float* __restrict__ fc1w,
                             const float* __restrict__ fc1b, const float* __restrict__ bn1g,
                             const float* __restrict__ bn1b, float* __restrict__ t1n) {
    __shared__ float sp[64 * 65];
    __shared__ float w1s[64 * 16];
    __shared__ float t1s[64 * 17];
    __shared__ float sA[16], sB[16];
    int t = threadIdx.x;
    int c0 = blockIdx.x * 16;
    for (int i = t; i < 4096; i += 256) { int r = i >> 6, cc = i & 63; sp[r * 65 + cc] = p[i]; }
    for (int i = t; i < 1024; i += 256) { int r = i >> 4, cc = i & 15; w1s[i] = fc1w[r * 128 + c0 + cc]; }
    __syncthreads();
    int r16 = t >> 4, c = t & 15;
    float b = fc1b[c0 + c];
#pragma unroll
    for (int rb = 0; rb < 4; rb++) {
        int row = rb * 16 + r16;
        float s = b;
#pragma unroll 8
        for (int i = 0; i < 64; i++) s += sp[row * 65 + i] * w1s[i * 16 + c];
        t1s[row * 17 + c] = s;
    }
    __syncthreads();
    if (t < 16) {
        float su = 0.f, sq = 0.f;
        for (int r = 0; r < 64; r++) { float v = t1s[r * 17 + t]; su += v; sq += v * v; }
        float mean = su * (1.f / 64.f), var = sq * (1.f / 64.f) - mean * mean;
        float sc = rsqrtf(var + 1e-5f) * bn1g[c0 + t];
        sA[t] = sc; sB[t] = bn1b[c0 + t] - mean * sc;
    }
    __syncthreads();
#pragma unroll
    for (int rb = 0; rb < 4; rb++) {
        int row = rb * 16 + r16;
        float v = t1s[row * 17 + c] * sA[c] + sB[c];
        t1n[row * 128 + c0 + c] = fmaxf(v, 0.f);
    }
}

// ---------------- head: fc2 + bn2 + relu (block owns 8 cols) ----------------
__global__ void head2_kernel(const float* __restrict__ t1n, const float* __restrict__ fc2w,
                             const float* __restrict__ fc2b, const float* __restrict__ bn2g,
                             const float* __restrict__ bn2b, float* __restrict__ y2n) {
    __shared__ float t1sh[64 * 129];
    __shared__ float w2s[128 * 8];
    __shared__ float t2s[64 * 9];
    __shared__ float sA[8], sB[8];
    int t = threadIdx.x;
    int c0 = blockIdx.x * 8;
    for (int i = t; i < 8192; i += 256) { int r = i >> 7, cc = i & 127; t1sh[r * 129 + cc] = t1n[i]; }
    for (int i = t; i < 1024; i += 256) { int r = i >> 3, cc = i & 7; w2s[i] = fc2w[r * 64 + c0 + cc]; }
    __syncthreads();
    int r32 = t >> 3, c = t & 7;
    float b = fc2b[c0 + c];
#pragma unroll
    for (int rb = 0; rb < 2; rb++) {
        int row = rb * 32 + r32;
        float s = b;
#pragma unroll 8
        for (int i = 0; i < 128; i++) s += t1sh[row * 129 + i] * w2s[i * 8 + c];
        t2s[row * 9 + c] = s;
    }
    __syncthreads();
    if (t < 8) {
        float su = 0.f, sq = 0.f;
        for (int r = 0; r < 64; r++) { float v = t2s[r * 9 + t]; su += v; sq += v * v; }
        float mean = su * (1.f / 64.f), var = sq * (1.f / 64.f) - mean * mean;
        float sc = rsqrtf(var + 1e-5f) * bn2g[c0 + t];
        sA[t] = sc; sB[t] = bn2b[c0 + t] - mean * sc;
    }
    __syncthreads();
#pragma unroll
    for (int rb = 0; rb < 2; rb++) {
        int row = rb * 32 + r32;
        float v = t2s[row * 9 + c] * sA[c] + sB[c];
        y2n[row * 64 + c0 + c] = fmaxf(v, 0.f);
    }
}

// ---------------- head: fc3 dot ----------------
__global__ void head3_kernel(const float* __restrict__ y2n, const float* __restrict__ fc3w,
                             const float* __restrict__ fc3b, float* __restrict__ out) {
    __shared__ float w3[64];
    int t = threadIdx.x;  // 64 threads
    w3[t] = fc3w[t];
    __syncthreads();
    float s = fc3b[0];
    const float* yr = y2n + t * 64;
#pragma unroll 8
    for (int i = 0; i < 64; i++) s += yr[i] * w3[i];
    out[t] = s;
}

extern "C" void kernel_launch(void* const* d_in, const int* in_sizes, int n_in,
                              void* d_out, int out_size, void* d_ws, size_t ws_size,
                              hipStream_t stream) {
    const float* x     = (const float*)d_in[0];
    const int*   eidx  = (const int*)d_in[1];
    const float* eattr = (const float*)d_in[2];
    const int*   batch = (const int*)d_in[3];
    const float* e1w1 = (const float*)d_in[4];  const float* e1b1 = (const float*)d_in[5];
    const float* e1w2 = (const float*)d_in[6];  const float* e1b2 = (const float*)d_in[7];
    const float* r1w  = (const float*)d_in[8];  const float* r1b  = (const float*)d_in[9];
    const float* bn1g = (const float*)d_in[10]; const float* bn1b = (const float*)d_in[11];
    const float* e2w1 = (const float*)d_in[12]; const float* e2b1 = (const float*)d_in[13];
    const float* e2w2 = (const float*)d_in[14]; const float* e2b2 = (const float*)d_in[15];
    const float* r2w  = (const float*)d_in[16]; const float* r2b  = (const float*)d_in[17];
    const float* bn2g = (const float*)d_in[18]; const float* bn2b = (const float*)d_in[19];
    const float* e3w1 = (const float*)d_in[20]; const float* e3b1 = (const float*)d_in[21];
    const float* e3w2 = (const float*)d_in[22]; const float* e3b2 = (const float*)d_in[23];
    const float* r3w  = (const float*)d_in[24]; const float* r3b  = (const float*)d_in[25];
    const float* bn3g = (const float*)d_in[26]; const float* bn3b = (const float*)d_in[27];
    const float* gw1  = (const float*)d_in[28]; const float* gb1  = (const float*)d_in[29];
    const float* gw2  = (const float*)d_in[30]; const float* gb2  = (const float*)d_in[31];
    const float* fc1w = (const float*)d_in[32]; const float* fc1b = (const float*)d_in[33];
    const float* fbn1g= (const float*)d_in[34]; const float* fbn1b= (const float*)d_in[35];
    const float* fc2w = (const float*)d_in[36]; const float* fc2b = (const float*)d_in[37];
    const float* fbn2g= (const float*)d_in[38]; const float* fbn2b= (const float*)d_in[39];
    const float* fc3w = (const float*)d_in[40]; const float* fc3b = (const float*)d_in[41];
    float* out = (float*)d_out;

    const int* src = eidx;
    const int* dst = eidx + EE;

    char* ws = (char*)d_ws;
    size_t off = 0;
    auto take = [&](size_t n) { void* p = ws + off; off = (off + n + 255) & ~(size_t)255; return p; };
    // 66 tiles each: tile 65 is pair-staging slack (staged, never computed)
    ushort_t* Bt1 = (ushort_t*)take((size_t)66 * 2048 * 2);
    ushort_t* Bt2 = (ushort_t*)take((size_t)66 * 4096 * 2);
    ushort_t* Bt3 = (ushort_t*)take((size_t)66 * 4096 * 2);
    float* msg  = (float*)take((size_t)EE * 64 * 4);
    float* ybuf = (float*)take((size_t)NN * 64 * 4);
    float* x1   = (float*)take((size_t)NN * 64 * 4);
    float* x2   = (float*)take((size_t)NN * 64 * 4);
    float* x3   = (float*)take((size_t)NN * 64 * 4);
    float* rootbuf = (float*)take((size_t)NN * 64 * 4);
    float* gate = (float*)take((size_t)NN * 4);
    float* pbuf = (float*)take(64 * 64 * 4);
    float* t1n  = (float*)take(64 * 128 * 4);
    float* y2n  = (float*)take(64 * 64 * 4);
    float* stats = (float*)take(384 * 4);
    int* cnt  = (int*)take((size_t)NN * 4);
    int* fill = (int*)take((size_t)NN * 4);
    int* rowp = (int*)take((size_t)(NN + 1) * 4);
    int* perm = (int*)take((size_t)EE * 4);

    btbuild_all_kernel<<<741, 256, 0, stream>>>(e1w2, e1b2, Bt1, e2w2, e2b2, Bt2,
                                                e3w2, e3b2, Bt3, cnt, fill, stats,
                                                x, r1w, r1b, rootbuf);
    hist_kernel<<<160, 256, 0, stream>>>(dst, cnt);
    scan_kernel<<<1, 1024, 0, stream>>>(cnt, rowp);
    scatter_kernel<<<160, 256, 0, stream>>>(dst, rowp, fill, perm);

    // layer 1 (IC = 32, pair-phase)
    conv_msg_pair_kernel<32><<<1280, 256, 0, stream>>>(eattr, e1w1, e1b1, x, src, perm, Bt1, msg);
    aggregate_kernel<<<512, 256, 0, stream>>>(msg, rowp, rootbuf, ybuf, stats);
    bn_apply_root_kernel<<<512, 256, 0, stream>>>(ybuf, stats, bn1g, bn1b, nullptr, x1,
                                                  r2w, r2b, rootbuf);

    // layer 2 (IC = 64, pair-phase, 4 blocks/CU via bf16 h_t)
    conv_msg_pair_kernel<64><<<1280, 256, 0, stream>>>(eattr, e2w1, e2b1, x1, src, perm, Bt2, msg);
    aggregate_kernel<<<512, 256, 0, stream>>>(msg, rowp, rootbuf, ybuf, stats + 128);
    bn_apply_root_kernel<<<512, 256, 0, stream>>>(ybuf, stats + 128, bn2g, bn2b, x1, x2,
                                                  r3w, r3b, rootbuf);

    // layer 3 (IC = 64, pair-phase)
    conv_msg_pair_kernel<64><<<1280, 256, 0, stream>>>(eattr, e3w1, e3b1, x2, src, perm, Bt3, msg);
    aggregate_kernel<<<512, 256, 0, stream>>>(msg, rowp, rootbuf, ybuf, stats + 256);
    bn_gate_kernel<<<128, 256, 0, stream>>>(ybuf, stats + 256, bn3g, bn3b, x2, x3,
                                            gw1, gb1, gw2, gb2, gate);

    attn_pool_kernel<<<64, 256, 0, stream>>>(x3, gate, batch, pbuf);
    head1_kernel<<<8, 256, 0, stream>>>(pbuf, fc1w, fc1b, fbn1g, fbn1b, t1n);
    head2_kernel<<<8, 256, 0, stream>>>(t1n, fc2w, fc2b, fbn2g, fbn2b, y2n);
    head3_kernel<<<1, 64, 0, stream>>>(y2n, fc3w, fc3b, out);
}

// Round 18
// 229.866 us; speedup vs baseline: 1.0588x; 1.0588x over previous
//
#include <hip/hip_runtime.h>
#include <hip/hip_bf16.h>

#define NN 8192
#define EE 40960
#define FIN 32
#define HH 64
#define GG 64

typedef __attribute__((ext_vector_type(4))) float f32x4;
typedef __attribute__((ext_vector_type(8))) short s16x8;
typedef unsigned short ushort_t;

__device__ __forceinline__ unsigned short f2bf(float f) {
    union { float f; unsigned int u; } v; v.f = f;
    unsigned int u = v.u;
    return (unsigned short)((u + 0x7fffu + ((u >> 16) & 1u)) >> 16);
}

__device__ __forceinline__ void gll16(const void* g, void* l) {
    // async global -> LDS, 16B per lane; LDS dest = wave-uniform base + lane*16
    __builtin_amdgcn_global_load_lds((__attribute__((address_space(1))) void*)g,
                                     (__attribute__((address_space(3))) void*)l, 16, 0, 0);
}

// ---------------- Bt build (coalesced LDS-transpose) + zeroing + layer-1 root -------
__global__ void btbuild_all_kernel(const float* __restrict__ w2a, const float* __restrict__ b2a, ushort_t* __restrict__ Bta,
                                   const float* __restrict__ w2b, const float* __restrict__ b2b, ushort_t* __restrict__ Btb,
                                   const float* __restrict__ w2c, const float* __restrict__ b2c, ushort_t* __restrict__ Btc,
                                   int* __restrict__ cnt, int* __restrict__ fill, float* __restrict__ stats,
                                   const float* __restrict__ x, const float* __restrict__ r1w,
                                   const float* __restrict__ r1b, float* __restrict__ rootbuf) {
    int bid = blockIdx.x;
    int t = threadIdx.x;

    if (bid < 195) {                          // Bt transpose, one (layer, step) per block
        __shared__ float ws[64 * 65];         // [i][o] padded: bank-conflict-free reads
        const float* w2; const float* b2; ushort_t* Bt; int IC, sh, s;
        if (bid < 65)       { w2 = w2a; b2 = b2a; Bt = Bta; IC = 32; sh = 5; s = bid; }
        else if (bid < 130) { w2 = w2b; b2 = b2b; Bt = Btb; IC = 64; sh = 6; s = bid - 65; }
        else                { w2 = w2c; b2 = b2c; Bt = Btc; IC = 64; sh = 6; s = bid - 130; }
        const int CH = IC >> 3;
        const int NEL = IC * 64;
        const float* src = (s < 64) ? (w2 + (size_t)s * NEL) : b2;
        for (int idx = t; idx < NEL; idx += 256) {     // coalesced: consecutive o
            int i = idx >> 6, o = idx & 63;
            ws[i * 65 + o] = src[idx];
        }
        __syncthreads();
        ushort_t* dst = Bt + (size_t)s * NEL;
        for (int fl = t; fl < NEL; fl += 256) {        // coalesced ushort stores
            int row = fl >> sh;
            int j = fl & (IC - 1);
            int q = j >> 3, w = j & 7;
            int c = q ^ (row & (CH - 1));
            int i = c * 8 + w;
            dst[fl] = f2bf(ws[i * 65 + row]);
        }
        return;
    }
    if (bid < 227) {                          // zero cnt/fill
        int b = bid - 195;
        cnt[b * 256 + t] = 0; fill[b * 256 + t] = 0;
        return;
    }
    if (bid == 227) { stats[t] = 0.f; return; }
    if (bid == 228) { if (t < 128) stats[256 + t] = 0.f; return; }

    // layer-1 root: 512 blocks, 16 nodes each
    {
        __shared__ float xs[16][36];
        __shared__ float rws[32 * 64];
        __shared__ float rbs[64];
        int blk = bid - 229;
        for (int j = t; j < 512; j += 256) { int r = j >> 5, i = j & 31; xs[r][i] = x[(size_t)(blk * 16 + r) * 32 + i]; }
        for (int i = t; i < 2048; i += 256) rws[i] = r1w[i];
        if (t < 64) rbs[t] = r1b[t];
        __syncthreads();
        int r = t >> 4, cg = (t & 15) * 4;
        f32x4 s = *(const f32x4*)&rbs[cg];
#pragma unroll 8
        for (int i = 0; i < 32; i++) {
            float xv = xs[r][i];
            s += xv * (*(const f32x4*)&rws[i * 64 + cg]);
        }
        *(f32x4*)&rootbuf[(size_t)(blk * 16 + r) * 64 + cg] = s;
    }
}

// ---------------- CSR build ----------------
__global__ void hist_kernel(const int* __restrict__ dst, int* __restrict__ cnt) {
    int e = blockIdx.x * 256 + threadIdx.x;
    if (e < EE) atomicAdd(&cnt[dst[e]], 1);
}

__global__ void scan_kernel(const int* __restrict__ cnt, int* __restrict__ row_ptr) {
    __shared__ int lds[1024];
    int t = threadIdx.x;
    int v[8]; int s = 0;
    int base = t * 8;
#pragma unroll
    for (int j = 0; j < 8; j++) { v[j] = s; s += cnt[base + j]; }
    lds[t] = s;
    __syncthreads();
    for (int off = 1; off < 1024; off <<= 1) {
        int add = (t >= off) ? lds[t - off] : 0;
        __syncthreads();
        lds[t] += add;
        __syncthreads();
    }
    int ex = lds[t] - s;
#pragma unroll
    for (int j = 0; j < 8; j++) row_ptr[base + j] = ex + v[j];
    if (t == 1023) row_ptr[NN] = lds[1023];
}

__global__ void scatter_kernel(const int* __restrict__ dst, const int* __restrict__ row_ptr,
                               int* __restrict__ fill, int* __restrict__ perm) {
    int e = blockIdx.x * 256 + threadIdx.x;
    if (e < EE) {
        int d = dst[e];
        int pos = row_ptr[d] + atomicAdd(&fill[d], 1);
        perm[pos] = e;
    }
}

// ---------------- NNConv message GEMM, IC=64 (32 edges/block, 1 step/barrier) ----
template<int IC>
__launch_bounds__(256, 5)
__global__ void conv_msg_kernel(const float* __restrict__ eattr,
                                const float* __restrict__ w1,
                                const float* __restrict__ b1,
                                const float* __restrict__ xin,
                                const int* __restrict__ src,
                                const int* __restrict__ perm,
                                const ushort_t* __restrict__ Bt,
                                float* __restrict__ msg) {
    constexpr int NKK  = IC / 32;
    constexpr int CH   = IC / 8;
    constexpr int TILE = IC * 64;
    constexpr int NQ   = (TILE * 2) / 4096;
    __shared__ ushort_t bt_lds[2][TILE];
    __shared__ float h_t[2048];
    __shared__ float ea_s[32][9];
    __shared__ float w1s[512];
    __shared__ float b1s[64];
    __shared__ int eid_s[32];

    const int t = threadIdx.x;
    const int wave = t >> 6;
    const int l = t & 63;
    const int g = l >> 4;
    const int rlo = l & 15;
    const int e0 = blockIdx.x * 32;

    auto stage = [&](int buf, int step) {
#pragma unroll
        for (int q = 0; q < NQ; ++q) {
            int off = q * 2048 + wave * 512;
            const ushort_t* gp = Bt + (size_t)step * TILE + off + l * 8;
            gll16(gp, &bt_lds[buf][off]);
        }
    };

    stage(0, 0);

    if (t < 32) eid_s[t] = perm[e0 + t];
    if (t < 64) b1s[t] = b1[t];
    for (int i = t; i < 512; i += 256) w1s[i] = w1[i];
    __syncthreads();

    { int e = t >> 3, i = t & 7; ea_s[e][i] = eattr[(size_t)eid_s[e] * 8 + i]; }

    s16x8 afrag[2][NKK];
#pragma unroll
    for (int m = 0; m < 2; ++m) {
        int row = m * 16 + rlo;
        int sn = src[eid_s[row]];
        const float* xp = xin + (size_t)sn * IC + g * 8;
#pragma unroll
        for (int kk = 0; kk < NKK; ++kk) {
            f32x4 a = *(const f32x4*)(xp + kk * 32);
            f32x4 b = *(const f32x4*)(xp + kk * 32 + 4);
            s16x8 fr;
            fr[0] = (short)f2bf(a[0]); fr[1] = (short)f2bf(a[1]);
            fr[2] = (short)f2bf(a[2]); fr[3] = (short)f2bf(a[3]);
            fr[4] = (short)f2bf(b[0]); fr[5] = (short)f2bf(b[1]);
            fr[6] = (short)f2bf(b[2]); fr[7] = (short)f2bf(b[3]);
            afrag[m][kk] = fr;
        }
    }
    __syncthreads();

#pragma unroll
    for (int j = 0; j < 8; ++j) {
        int idx = t + 256 * j;
        int k = idx >> 5, e = idx & 31;
        float s = b1s[k];
#pragma unroll
        for (int i = 0; i < 8; i++) s += ea_s[e][i] * w1s[i * 64 + k];
        h_t[idx] = fmaxf(s, 0.f);
    }
    __syncthreads();

    f32x4 acc[2];
#pragma unroll
    for (int m = 0; m < 2; m++) acc[m] = (f32x4){0.f, 0.f, 0.f, 0.f};

    const int bcol = wave * 16 + rlo;
    const int bmask = bcol & (CH - 1);
    const f32x4 zf = (f32x4){0.f, 0.f, 0.f, 0.f};

    for (int step = 0; step < 65; ++step) {
        if (step < 64) stage((step + 1) & 1, step + 1);
        const int buf = step & 1;
        s16x8 bfr[NKK];
#pragma unroll
        for (int kk = 0; kk < NKK; kk++) {
            int q = (kk * 4 + g) ^ bmask;
            bfr[kk] = *(const s16x8*)&bt_lds[buf][bcol * IC + q * 8];
        }
#pragma unroll
        for (int m = 0; m < 2; m++) {
            f32x4 P = __builtin_amdgcn_mfma_f32_16x16x32_bf16(afrag[m][0], bfr[0], zf, 0, 0, 0);
            if constexpr (NKK == 2)
                P = __builtin_amdgcn_mfma_f32_16x16x32_bf16(afrag[m][1], bfr[1], P, 0, 0, 0);
            if (step == 64) {
                acc[m] += P;
            } else {
                f32x4 h4 = *(const f32x4*)&h_t[(step << 5) + m * 16 + (g << 2)];
                acc[m] += h4 * P;
            }
        }
        __syncthreads();
    }

#pragma unroll
    for (int m = 0; m < 2; m++) {
        int row = e0 + m * 16 + (g << 2);
        float* mp = msg + (size_t)row * 64 + wave * 16 + rlo;
        mp[0] = acc[m][0]; mp[64] = acc[m][1]; mp[128] = acc[m][2]; mp[192] = acc[m][3];
    }
}

// ---------------- NNConv message GEMM, IC=32 pair-phase (2 steps/barrier) ----
template<int IC>
__launch_bounds__(256, 5)
__global__ void conv_msg_pair_kernel(const float* __restrict__ eattr,
                                     const float* __restrict__ w1,
                                     const float* __restrict__ b1,
                                     const float* __restrict__ xin,
                                     const int* __restrict__ src,
                                     const int* __restrict__ perm,
                                     const ushort_t* __restrict__ Bt,
                                     float* __restrict__ msg) {
    constexpr int NKK  = IC / 32;
    constexpr int CH   = IC / 8;
    constexpr int TILE = IC * 64;
    constexpr int NQT  = TILE / 2048;    // 1 for IC=32
    __shared__ ushort_t bt_lds[2][2 * TILE];
    __shared__ float h_t[2048];
    __shared__ float ea_s[32][9];
    __shared__ float w1s[512];
    __shared__ float b1s[64];
    __shared__ int eid_s[32];

    const int t = threadIdx.x;
    const int wave = t >> 6;
    const int l = t & 63;
    const int g = l >> 4;
    const int rlo = l & 15;
    const int e0 = blockIdx.x * 32;

    auto stage = [&](int buf, int phase) {
#pragma unroll
        for (int q = 0; q < 2 * NQT; ++q) {
            int off = q * 2048 + wave * 512;
            const ushort_t* gp = Bt + (size_t)(2 * phase) * TILE + off + l * 8;
            gll16(gp, &bt_lds[buf][off]);
        }
    };

    stage(0, 0);

    if (t < 32) eid_s[t] = perm[e0 + t];
    if (t < 64) b1s[t] = b1[t];
    for (int i = t; i < 512; i += 256) w1s[i] = w1[i];
    __syncthreads();

    { int e = t >> 3, i = t & 7; ea_s[e][i] = eattr[(size_t)eid_s[e] * 8 + i]; }

    s16x8 afrag[2][NKK];
#pragma unroll
    for (int m = 0; m < 2; ++m) {
        int row = m * 16 + rlo;
        int sn = src[eid_s[row]];
        const float* xp = xin + (size_t)sn * IC + g * 8;
#pragma unroll
        for (int kk = 0; kk < NKK; ++kk) {
            f32x4 a = *(const f32x4*)(xp + kk * 32);
            f32x4 b = *(const f32x4*)(xp + kk * 32 + 4);
            s16x8 fr;
            fr[0] = (short)f2bf(a[0]); fr[1] = (short)f2bf(a[1]);
            fr[2] = (short)f2bf(a[2]); fr[3] = (short)f2bf(a[3]);
            fr[4] = (short)f2bf(b[0]); fr[5] = (short)f2bf(b[1]);
            fr[6] = (short)f2bf(b[2]); fr[7] = (short)f2bf(b[3]);
            afrag[m][kk] = fr;
        }
    }
    __syncthreads();

#pragma unroll
    for (int j = 0; j < 8; ++j) {
        int idx = t + 256 * j;
        int k = idx >> 5, e = idx & 31;
        float s = b1s[k];
#pragma unroll
        for (int i = 0; i < 8; i++) s += ea_s[e][i] * w1s[i * 64 + k];
        h_t[idx] = fmaxf(s, 0.f);
    }
    __syncthreads();

    f32x4 acc[2];
#pragma unroll
    for (int m = 0; m < 2; m++) acc[m] = (f32x4){0.f, 0.f, 0.f, 0.f};

    const int bcol = wave * 16 + rlo;
    const int bmask = bcol & (CH - 1);
    const f32x4 zf = (f32x4){0.f, 0.f, 0.f, 0.f};

    auto compute = [&](int buf, int sub, int step) {
        s16x8 bfr[NKK];
#pragma unroll
        for (int kk = 0; kk < NKK; kk++) {
            int q = (kk * 4 + g) ^ bmask;
            bfr[kk] = *(const s16x8*)&bt_lds[buf][sub * TILE + bcol * IC + q * 8];
        }
#pragma unroll
        for (int m = 0; m < 2; m++) {
            f32x4 P = __builtin_amdgcn_mfma_f32_16x16x32_bf16(afrag[m][0], bfr[0], zf, 0, 0, 0);
            if constexpr (NKK == 2)
                P = __builtin_amdgcn_mfma_f32_16x16x32_bf16(afrag[m][1], bfr[1], P, 0, 0, 0);
            if (step == 64) {
                acc[m] += P;
            } else {
                f32x4 h4 = *(const f32x4*)&h_t[(step << 5) + m * 16 + (g << 2)];
                acc[m] += h4 * P;
            }
        }
    };

    for (int ph = 0; ph < 33; ++ph) {
        if (ph < 32) stage((ph + 1) & 1, ph + 1);
        const int buf = ph & 1;
        compute(buf, 0, 2 * ph);
        if (ph < 32) compute(buf, 1, 2 * ph + 1);
        __syncthreads();
    }

#pragma unroll
    for (int m = 0; m < 2; m++) {
        int row = e0 + m * 16 + (g << 2);
        float* mp = msg + (size_t)row * 64 + wave * 16 + rlo;
        mp[0] = acc[m][0]; mp[64] = acc[m][1]; mp[128] = acc[m][2]; mp[192] = acc[m][3];
    }
}

// ---------------- aggregate: y = seg_mean(msg) + rootbuf; fused BN stats ----------------
__global__ void aggregate_kernel(const float* __restrict__ msg, const int* __restrict__ row_ptr,
                                 const float* __restrict__ rootbuf,
                                 float* __restrict__ y, float* __restrict__ stats) {
    int t = threadIdx.x;
    int n = blockIdx.x * 16 + (t >> 4);
    int cg = (t & 15) * 4;
    int s = row_ptr[n], e = row_ptr[n + 1];
    f32x4 acc = (f32x4){0.f, 0.f, 0.f, 0.f};
    for (int j = s; j < e; ++j) {
        acc += *(const f32x4*)&msg[(size_t)j * 64 + cg];   // contiguous (dst-sorted)
    }
    float inv = 1.0f / fmaxf((float)(e - s), 1.0f);
    acc *= inv;
    acc += *(const f32x4*)&rootbuf[(size_t)n * 64 + cg];   // x@root_w + root_b (precomputed)
    *(f32x4*)&y[(size_t)n * 64 + cg] = acc;

    f32x4 a2 = acc * acc;
#pragma unroll
    for (int j = 0; j < 4; j++) {
        acc[j] += __shfl_xor(acc[j], 16); acc[j] += __shfl_xor(acc[j], 32);
        a2[j]  += __shfl_xor(a2[j], 16);  a2[j]  += __shfl_xor(a2[j], 32);
    }
    __shared__ float ls[4][64], lq[4][64];
    int w = t >> 6;
    if ((t & 63) < 16) {
#pragma unroll
        for (int j = 0; j < 4; j++) { ls[w][cg + j] = acc[j]; lq[w][cg + j] = a2[j]; }
    }
    __syncthreads();
    if (t < 64) {
        float S = ls[0][t] + ls[1][t] + ls[2][t] + ls[3][t];
        float Q = lq[0][t] + lq[1][t] + lq[2][t] + lq[3][t];
        atomicAdd(&stats[t], S);
        atomicAdd(&stats[64 + t], Q);
    }
}

// ---------------- BN apply + relu (+ residual) + NEXT layer's root GEMM ----------------
__global__ void bn_apply_root_kernel(const float* __restrict__ y, const float* __restrict__ stats,
                                     const float* __restrict__ gam, const float* __restrict__ bet,
                                     const float* __restrict__ res, float* __restrict__ xout,
                                     const float* __restrict__ rw, const float* __restrict__ rb,
                                     float* __restrict__ rootbuf) {
    __shared__ float xs[16][68];
    __shared__ float rws[64 * 64];   // 16 KB
    __shared__ float rbs[64];
    int t = threadIdx.x;
    for (int i = t; i < 4096; i += 256) rws[i] = rw[i];
    if (t < 64) rbs[t] = rb[t];
    int i4 = blockIdx.x * 256 + t;
    int row = t >> 4, cg = (t & 15) * 4;
    const float invN = 1.0f / (float)NN;
    f32x4 yv = *(const f32x4*)&y[(size_t)i4 * 4];
    f32x4 o;
#pragma unroll
    for (int j = 0; j < 4; j++) {
        int c = cg + j;
        float mean = stats[c] * invN;
        float var = stats[64 + c] * invN - mean * mean;
        float sc = rsqrtf(var + 1e-5f) * gam[c];
        o[j] = fmaxf((yv[j] - mean) * sc + bet[c], 0.f);
    }
    if (res) o += *(const f32x4*)&res[(size_t)i4 * 4];
    *(f32x4*)&xout[(size_t)i4 * 4] = o;
    *(f32x4*)&xs[row][cg] = o;
    __syncthreads();
    f32x4 s = *(const f32x4*)&rbs[cg];
#pragma unroll 8
    for (int i = 0; i < 64; i++) {
        float xv = xs[row][i];
        s += xv * (*(const f32x4*)&rws[i * 64 + cg]);
    }
    *(f32x4*)&rootbuf[(size_t)(blockIdx.x * 16 + row) * 64 + cg] = s;
}

// ---------------- BN3 + relu + residual + attention-gate (fused) ----------------
__global__ void bn_gate_kernel(const float* __restrict__ y, const float* __restrict__ stats,
                               const float* __restrict__ gam, const float* __restrict__ bet,
                               const float* __restrict__ res, float* __restrict__ xout,
                               const float* __restrict__ gw1, const float* __restrict__ gb1,
                               const float* __restrict__ gw2, const float* __restrict__ gb2,
                               float* __restrict__ gate) {
    __shared__ float x3s[64][68];   // stride 68: 16B-aligned f32x4 slots
    __shared__ float w1s[2048];
    __shared__ float b1s[32], w2s[32];
    __shared__ float b2s;
    int t = threadIdx.x;
    for (int i = t; i < 2048; i += 256) w1s[i] = gw1[i];
    if (t < 32) { b1s[t] = gb1[t]; w2s[t] = gw2[t]; }
    if (t == 0) b2s = gb2[0];
    const float invN = 1.0f / (float)NN;
    size_t base4 = (size_t)blockIdx.x * 1024;   // block covers 64 rows = 1024 f32x4
#pragma unroll
    for (int j = 0; j < 4; j++) {
        int i4l = j * 256 + t;
        int row = i4l >> 4, cg = (i4l & 15) * 4;
        f32x4 yv = *(const f32x4*)&y[(base4 + i4l) * 4];
        f32x4 o;
#pragma unroll
        for (int jj = 0; jj < 4; jj++) {
            int c = cg + jj;
            float mean = stats[c] * invN;
            float var = stats[64 + c] * invN - mean * mean;
            float sc = rsqrtf(var + 1e-5f) * gam[c];
            o[jj] = fmaxf((yv[jj] - mean) * sc + bet[c], 0.f);
        }
        o += *(const f32x4*)&res[(base4 + i4l) * 4];
        *(f32x4*)&xout[(base4 + i4l) * 4] = o;
        *(f32x4*)&x3s[row][cg] = o;
    }
    __syncthreads();
    // gate: 4 lanes per row, 8 hidden units each
    int w = t >> 6, l = t & 63;
    int row = w * 16 + (l >> 2), part = l & 3;
    float hacc[8];
#pragma unroll
    for (int j = 0; j < 8; j++) hacc[j] = b1s[part * 8 + j];
    for (int i = 0; i < 64; i++) {
        float xv = x3s[row][i];
#pragma unroll
        for (int j = 0; j < 8; j++) hacc[j] += xv * w1s[i * 32 + part * 8 + j];
    }
    float gv = 0.f;
#pragma unroll
    for (int j = 0; j < 8; j++) gv += fmaxf(hacc[j], 0.f) * w2s[part * 8 + j];
    gv += __shfl_xor(gv, 1); gv += __shfl_xor(gv, 2);
    if (part == 0) gate[blockIdx.x * 64 + row] = gv + b2s;
}

// ---------------- per-group softmax-weighted pool ----------------
__global__ void attn_pool_kernel(const float* __restrict__ x3, const float* __restrict__ gate,
                                 const int* __restrict__ batch, float* __restrict__ p) {
    int g = blockIdx.x;
    int t = threadIdx.x;
    int lo = 0, hi = NN;
    while (lo < hi) { int mid = (lo + hi) >> 1; if (batch[mid] < g) lo = mid + 1; else hi = mid; }
    int s = lo;
    hi = NN;
    while (lo < hi) { int mid = (lo + hi) >> 1; if (batch[mid] < g + 1) lo = mid + 1; else hi = mid; }
    int e = lo;

    __shared__ float red[4];
    __shared__ float sM, sZ;
    float m = -1e30f;
    for (int n = s + t; n < e; n += 256) m = fmaxf(m, gate[n]);
#pragma unroll
    for (int off = 1; off < 64; off <<= 1) m = fmaxf(m, __shfl_xor(m, off));
    if ((t & 63) == 0) red[t >> 6] = m;
    __syncthreads();
    if (t == 0) sM = fmaxf(fmaxf(red[0], red[1]), fmaxf(red[2], red[3]));
    __syncthreads();
    float z = 0.f;
    for (int n = s + t; n < e; n += 256) z += __expf(gate[n] - sM);
#pragma unroll
    for (int off = 1; off < 64; off <<= 1) z += __shfl_xor(z, off);
    if ((t & 63) == 0) red[t >> 6] = z;
    __syncthreads();
    if (t == 0) sZ = red[0] + red[1] + red[2] + red[3];
    __syncthreads();
    int w = t >> 6, c = t & 63;
    float acc = 0.f;
    for (int n = s + w; n < e; n += 4) acc += __expf(gate[n] - sM) * x3[(size_t)n * 64 + c];
    __shared__ float pa[4][64];
    pa[w][c] = acc;
    __syncthreads();
    if (t < 64) {
        float v = pa[0][t] + pa[1][t] + pa[2][t] + pa[3][t];
        p[g * 64 + t] = (sZ > 0.f) ? v / sZ : 0.f;
    }
}

// ---------------- head: fc1 + bn1 + relu (block owns 16 cols -> local stats) ----------------
__global__ void head1_kernel(const float* __restrict__ p, const float* __restrict__ fc1w,
                             const float* __restrict__ fc1b, const float* __restrict__ bn1g,
                             const float* __restrict__ bn1b, float* __restrict__ t1n) {
    __shared__ float sp[64 * 65];
    __shared__ float w1s[64 * 16];
    __shared__ float t1s[64 * 17];
    __shared__ float sA[16], sB[16];
    int t = threadIdx.x;
    int c0 = blockIdx.x * 16;
    for (int i = t; i < 4096; i += 256) { int r = i >> 6, cc = i & 63; sp[r * 65 + cc] = p[i]; }
    for (int i = t; i < 1024; i += 256) { int r = i >> 4, cc = i & 15; w1s[i] = fc1w[r * 128 + c0 + cc]; }
    __syncthreads();
    int r16 = t >> 4, c = t & 15;
    float b = fc1b[c0 + c];
#pragma unroll
    for (int rb = 0; rb < 4; rb++) {
        int row = rb * 16 + r16;
        float s = b;
#pragma unroll 8
        for (int i = 0; i < 64; i++) s += sp[row * 65 + i] * w1s[i * 16 + c];
        t1s[row * 17 + c] = s;
    }
    __syncthreads();
    if (t < 16) {
        float su = 0.f, sq = 0.f;
        for (int r = 0; r < 64; r++) { float v = t1s[r * 17 + t]; su += v; sq += v * v; }
        float mean = su * (1.f / 64.f), var = sq * (1.f / 64.f) - mean * mean;
        float sc = rsqrtf(var + 1e-5f) * bn1g[c0 + t];
        sA[t] = sc; sB[t] = bn1b[c0 + t] - mean * sc;
    }
    __syncthreads();
#pragma unroll
    for (int rb = 0; rb < 4; rb++) {
        int row = rb * 16 + r16;
        float v = t1s[row * 17 + c] * sA[c] + sB[c];
        t1n[row * 128 + c0 + c] = fmaxf(v, 0.f);
    }
}

// ---------------- head: fc2 + bn2 + relu (block owns 8 cols) ----------------
__global__ void head2_kernel(const float* __restrict__ t1n, const float* __restrict__ fc2w,
                             const float* __restrict__ fc2b, const float* __restrict__ bn2g,
                             const float* __restrict__ bn2b, float* __restrict__ y2n) {
    __shared__ float t1sh[64 * 129];
    __shared__ float w2s[128 * 8];
    __shared__ float t2s[64 * 9];
    __shared__ float sA[8], sB[8];
    int t = threadIdx.x;
    int c0 = blockIdx.x * 8;
    for (int i = t; i < 8192; i += 256) { int r = i >> 7, cc = i & 127; t1sh[r * 129 + cc] = t1n[i]; }
    for (int i = t; i < 1024; i += 256) { int r = i >> 3, cc = i & 7; w2s[i] = fc2w[r * 64 + c0 + cc]; }
    __syncthreads();
    int r32 = t >> 3, c = t & 7;
    float b = fc2b[c0 + c];
#pragma unroll
    for (int rb = 0; rb < 2; rb++) {
        int row = rb * 32 + r32;
        float s = b;
#pragma unroll 8
        for (int i = 0; i < 128; i++) s += t1sh[row * 129 + i] * w2s[i * 8 + c];
        t2s[row * 9 + c] = s;
    }
    __syncthreads();
    if (t < 8) {
        float su = 0.f, sq = 0.f;
        for (int r = 0; r < 64; r++) { float v = t2s[r * 9 + t]; su += v; sq += v * v; }
        float mean = su * (1.f / 64.f), var = sq * (1.f / 64.f) - mean * mean;
        float sc = rsqrtf(var + 1e-5f) * bn2g[c0 + t];
        sA[t] = sc; sB[t] = bn2b[c0 + t] - mean * sc;
    }
    __syncthreads();
#pragma unroll
    for (int rb = 0; rb < 2; rb++) {
        int row = rb * 32 + r32;
        float v = t2s[row * 9 + c] * sA[c] + sB[c];
        y2n[row * 64 + c0 + c] = fmaxf(v, 0.f);
    }
}

// ---------------- head: fc3 dot ----------------
__global__ void head3_kernel(const float* __restrict__ y2n, const float* __restrict__ fc3w,
                             const float* __restrict__ fc3b, float* __restrict__ out) {
    __shared__ float w3[64];
    int t = threadIdx.x;  // 64 threads
    w3[t] = fc3w[t];
    __syncthreads();
    float s = fc3b[0];
    const float* yr = y2n + t * 64;
#pragma unroll 8
    for (int i = 0; i < 64; i++) s += yr[i] * w3[i];
    out[t] = s;
}

extern "C" void kernel_launch(void* const* d_in, const int* in_sizes, int n_in,
                              void* d_out, int out_size, void* d_ws, size_t ws_size,
                              hipStream_t stream) {
    const float* x     = (const float*)d_in[0];
    const int*   eidx  = (const int*)d_in[1];
    const float* eattr = (const float*)d_in[2];
    const int*   batch = (const int*)d_in[3];
    const float* e1w1 = (const float*)d_in[4];  const float* e1b1 = (const float*)d_in[5];
    const float* e1w2 = (const float*)d_in[6];  const float* e1b2 = (const float*)d_in[7];
    const float* r1w  = (const float*)d_in[8];  const float* r1b  = (const float*)d_in[9];
    const float* bn1g = (const float*)d_in[10]; const float* bn1b = (const float*)d_in[11];
    const float* e2w1 = (const float*)d_in[12]; const float* e2b1 = (const float*)d_in[13];
    const float* e2w2 = (const float*)d_in[14]; const float* e2b2 = (const float*)d_in[15];
    const float* r2w  = (const float*)d_in[16]; const float* r2b  = (const float*)d_in[17];
    const float* bn2g = (const float*)d_in[18]; const float* bn2b = (const float*)d_in[19];
    const float* e3w1 = (const float*)d_in[20]; const float* e3b1 = (const float*)d_in[21];
    const float* e3w2 = (const float*)d_in[22]; const float* e3b2 = (const float*)d_in[23];
    const float* r3w  = (const float*)d_in[24]; const float* r3b  = (const float*)d_in[25];
    const float* bn3g = (const float*)d_in[26]; const float* bn3b = (const float*)d_in[27];
    const float* gw1  = (const float*)d_in[28]; const float* gb1  = (const float*)d_in[29];
    const float* gw2  = (const float*)d_in[30]; const float* gb2  = (const float*)d_in[31];
    const float* fc1w = (const float*)d_in[32]; const float* fc1b = (const float*)d_in[33];
    const float* fbn1g= (const float*)d_in[34]; const float* fbn1b= (const float*)d_in[35];
    const float* fc2w = (const float*)d_in[36]; const float* fc2b = (const float*)d_in[37];
    const float* fbn2g= (const float*)d_in[38]; const float* fbn2b= (const float*)d_in[39];
    const float* fc3w = (const float*)d_in[40]; const float* fc3b = (const float*)d_in[41];
    float* out = (float*)d_out;

    const int* src = eidx;
    const int* dst = eidx + EE;

    char* ws = (char*)d_ws;
    size_t off = 0;
    auto take = [&](size_t n) { void* p = ws + off; off = (off + n + 255) & ~(size_t)255; return p; };
    // Bt1 gets 66 tiles (pair-staging slack: tile 65 staged, never computed)
    ushort_t* Bt1 = (ushort_t*)take((size_t)66 * 2048 * 2);
    ushort_t* Bt2 = (ushort_t*)take((size_t)65 * 4096 * 2);
    ushort_t* Bt3 = (ushort_t*)take((size_t)65 * 4096 * 2);
    float* msg  = (float*)take((size_t)EE * 64 * 4);
    float* ybuf = (float*)take((size_t)NN * 64 * 4);
    float* x1   = (float*)take((size_t)NN * 64 * 4);
    float* x2   = (float*)take((size_t)NN * 64 * 4);
    float* x3   = (float*)take((size_t)NN * 64 * 4);
    float* rootbuf = (float*)take((size_t)NN * 64 * 4);
    float* gate = (float*)take((size_t)NN * 4);
    float* pbuf = (float*)take(64 * 64 * 4);
    float* t1n  = (float*)take(64 * 128 * 4);
    float* y2n  = (float*)take(64 * 64 * 4);
    float* stats = (float*)take(384 * 4);
    int* cnt  = (int*)take((size_t)NN * 4);
    int* fill = (int*)take((size_t)NN * 4);
    int* rowp = (int*)take((size_t)(NN + 1) * 4);
    int* perm = (int*)take((size_t)EE * 4);

    btbuild_all_kernel<<<741, 256, 0, stream>>>(e1w2, e1b2, Bt1, e2w2, e2b2, Bt2,
                                                e3w2, e3b2, Bt3, cnt, fill, stats,
                                                x, r1w, r1b, rootbuf);
    hist_kernel<<<160, 256, 0, stream>>>(dst, cnt);
    scan_kernel<<<1, 1024, 0, stream>>>(cnt, rowp);
    scatter_kernel<<<160, 256, 0, stream>>>(dst, rowp, fill, perm);

    // layer 1 (IC = 32, pair-phase at 5 blocks/CU)
    conv_msg_pair_kernel<32><<<1280, 256, 0, stream>>>(eattr, e1w1, e1b1, x, src, perm, Bt1, msg);
    aggregate_kernel<<<512, 256, 0, stream>>>(msg, rowp, rootbuf, ybuf, stats);
    bn_apply_root_kernel<<<512, 256, 0, stream>>>(ybuf, stats, bn1g, bn1b, nullptr, x1,
                                                  r2w, r2b, rootbuf);

    // layer 2 (IC = 64)
    conv_msg_kernel<64><<<1280, 256, 0, stream>>>(eattr, e2w1, e2b1, x1, src, perm, Bt2, msg);
    aggregate_kernel<<<512, 256, 0, stream>>>(msg, rowp, rootbuf, ybuf, stats + 128);
    bn_apply_root_kernel<<<512, 256, 0, stream>>>(ybuf, stats + 128, bn2g, bn2b, x1, x2,
                                                  r3w, r3b, rootbuf);

    // layer 3 (IC = 64)
    conv_msg_kernel<64><<<1280, 256, 0, stream>>>(eattr, e3w1, e3b1, x2, src, perm, Bt3, msg);
    aggregate_kernel<<<512, 256, 0, stream>>>(msg, rowp, rootbuf, ybuf, stats + 256);
    bn_gate_kernel<<<128, 256, 0, stream>>>(ybuf, stats + 256, bn3g, bn3b, x2, x3,
                                            gw1, gb1, gw2, gb2, gate);

    attn_pool_kernel<<<64, 256, 0, stream>>>(x3, gate, batch, pbuf);
    head1_kernel<<<8, 256, 0, stream>>>(pbuf, fc1w, fc1b, fbn1g, fbn1b, t1n);
    head2_kernel<<<8, 256, 0, stream>>>(t1n, fc2w, fc2b, fbn2g, fbn2b, y2n);
    head3_kernel<<<1, 64, 0, stream>>>(y2n, fc3w, fc3b, out);
}